// Round 2
// baseline (1814.151 us; speedup 1.0000x reference)
//
#include <hip/hip_runtime.h>

// Problem: B=8, H=16, S=1024, D=64, fp32.
// d_out = context[B,H,S,D] (8,388,608 f32) ++ attn[B,H,S,S] (134,217,728 f32).
#define S_ 1024
#define D_ 64
#define CTX_ELEMS (8 * 16 * 1024 * 64)

// ---------------------------------------------------------------------------
// Mask dtype detector: scans first 1024 32-bit words of the mask buffer.
//   int32 mask  -> words in {0,1}            -> mode 0
//   uint8 mask  -> words with bytes {0,1}    -> some word > 1        -> bit0
//   float mask  -> words 0x00000000/0x3F800000 -> bit1
// ---------------------------------------------------------------------------
__global__ void detect_mask_kernel(const unsigned int* __restrict__ mask,
                                   int* __restrict__ flag) {
  const int t = threadIdx.x;
  if (t == 0) flag[0] = 0;
  __syncthreads();
  unsigned int local = 0;
  for (int i = t; i < 1024; i += 256) {
    unsigned int w = mask[i];
    if (w == 0x3F800000u)      local |= 2u;   // float 1.0 pattern
    else if (w > 1u)           local |= 1u;   // packed-byte pattern
  }
  if (local) atomicOr(flag, (int)local);
}

// ---------------------------------------------------------------------------
// Fused attention. R2 structure:
//  - 32-query tile per 256-thread block (8 rows per wave, acc[8][16]):
//    halves K/V staging traffic + barrier count per FLOP vs R1's 16-row tile,
//    doubles per-thread ILP (we are VGPR/LDS-capped at ~2 blocks/CU anyway).
//  - T14 async-stage: K/V tile t+1 is global-loaded into registers right
//    after tile t's LDS write; plain reg loads stay in flight across
//    s_barrier, so HBM latency hides under the tile-t compute. V tile 0 is
//    prefetched during the last K tile (in flight across mask+softmax).
//  - XCD-aware block decode: all 32 q-tiles of one bh map to one XCD ->
//    K/V stay in that XCD's private L2.
// ---------------------------------------------------------------------------
__global__ __launch_bounds__(256, 2)
void attn_fused_kernel(const float* __restrict__ Q, const float* __restrict__ K,
                       const float* __restrict__ V, const void* __restrict__ mask,
                       float* __restrict__ out, const int* __restrict__ flag) {
  // LDS: stride 17 float4 (=68 floats): measured 0 bank conflicts.
  __shared__ float4 Qs[32][17];     //  8.5 KB
  __shared__ float4 KVs[128][17];   // 34.8 KB (K tiles, then V tiles)
  __shared__ float  As[32][132];    // 16.9 KB (attn chunk for PV relayout)

  const int t = threadIdx.x;
  // XCD-aware decode: HW round-robins consecutive block ids over 8 XCDs.
  // Map so each XCD owns 16 whole bh's (all 32 q-tiles of a bh on one XCD).
  const int id   = blockIdx.x;          // 0..4095
  const int xcd  = id & 7;
  const int slot = id >> 3;             // 0..511
  const int bh   = xcd + 8 * (slot >> 5);   // 0..127
  const int qt   = slot & 31;               // 0..31
  const int q0   = qt * 32;

  const int qg = t >> 6;            // wave id = q-group (8 rows each)
  const int kl = t & 63;            // k lane

  const float* Qb = Q + (size_t)bh * (S_ * D_) + (size_t)q0 * D_;
  const float4* Kb4 = (const float4*)(K + (size_t)bh * (S_ * D_));
  const float4* Vb4 = (const float4*)(V + (size_t)bh * (S_ * D_));

  // ---- load Q tile (32x64 f32 = 512 float4, 2/thread, coalesced) ----
  {
#pragma unroll
    for (int i = 0; i < 2; ++i) {
      const int fi = t + 256 * i;
      Qs[fi >> 4][fi & 15] = ((const float4*)Qb)[fi];
    }
  }

  float acc[8][16];
#pragma unroll
  for (int qq = 0; qq < 8; ++qq)
#pragma unroll
    for (int ci = 0; ci < 16; ++ci) acc[qq][ci] = 0.f;

  // ---- Phase 1: scores = Q K^T, K staged via reg-prefetch double buffer ----
  float4 st[8];
#pragma unroll
  for (int i = 0; i < 8; ++i) st[i] = Kb4[t + 256 * i];   // K tile 0

#pragma unroll
  for (int kt = 0; kt < 8; ++kt) {
    __syncthreads();                         // KVs free (prev tile consumed)
#pragma unroll
    for (int i = 0; i < 8; ++i) {            // regs -> LDS (2048 float4/tile)
      const int fi = t + 256 * i;
      KVs[fi >> 4][fi & 15] = st[i];
    }
    if (kt < 7) {                            // prefetch next K tile
#pragma unroll
      for (int i = 0; i < 8; ++i) st[i] = Kb4[(kt + 1) * 2048 + t + 256 * i];
    } else {                                 // prefetch V tile 0
#pragma unroll
      for (int i = 0; i < 8; ++i) st[i] = Vb4[t + 256 * i];
    }
    __syncthreads();                         // tile kt ready
#pragma unroll
    for (int d4 = 0; d4 < 16; ++d4) {
      const float4 kv0 = KVs[kl][d4];        // k_local = kl      (ci = 2kt)
      const float4 kv1 = KVs[kl + 64][d4];   // k_local = kl + 64 (ci = 2kt+1)
#pragma unroll
      for (int qq = 0; qq < 8; ++qq) {
        const float4 qv = Qs[8 * qg + qq][d4];   // wave-broadcast
        acc[qq][2 * kt]     += qv.x * kv0.x + qv.y * kv0.y + qv.z * kv0.z + qv.w * kv0.w;
        acc[qq][2 * kt + 1] += qv.x * kv1.x + qv.y * kv1.y + qv.z * kv1.z + qv.w * kv1.w;
      }
    }
  }

  // ---- mask + scale (mode branch is wave-uniform; k = 64*ci + kl) ----
  const float scale = 0.125f;                     // 1/sqrt(64)
  const int mode = *flag;
  const size_t mbase = (size_t)bh * ((size_t)S_ * S_) + (size_t)q0 * S_;
  if (mode & 2) {                                 // float32 mask
    const float* mf = (const float*)mask + mbase;
#pragma unroll
    for (int qq = 0; qq < 8; ++qq) {
      const float* mr = mf + (8 * qg + qq) * S_ + kl;
#pragma unroll
      for (int ci = 0; ci < 16; ++ci)
        acc[qq][ci] = (mr[64 * ci] != 0.f) ? -1e9f : acc[qq][ci] * scale;
    }
  } else if (mode & 1) {                          // uint8 mask
    const unsigned char* mu = (const unsigned char*)mask + mbase;
#pragma unroll
    for (int qq = 0; qq < 8; ++qq) {
      const unsigned char* mr = mu + (8 * qg + qq) * S_ + kl;
#pragma unroll
      for (int ci = 0; ci < 16; ++ci)
        acc[qq][ci] = mr[64 * ci] ? -1e9f : acc[qq][ci] * scale;
    }
  } else {                                        // int32 mask
    const int* mi = (const int*)mask + mbase;
#pragma unroll
    for (int qq = 0; qq < 8; ++qq) {
      const int* mr = mi + (8 * qg + qq) * S_ + kl;
#pragma unroll
      for (int ci = 0; ci < 16; ++ci)
        acc[qq][ci] = mr[64 * ci] ? -1e9f : acc[qq][ci] * scale;
    }
  }

  // ---- softmax per row: full-wave shuffle reductions ----
  float* outAttn = out + CTX_ELEMS;
#pragma unroll
  for (int qq = 0; qq < 8; ++qq) {
    float mx = -3.4e38f;
#pragma unroll
    for (int ci = 0; ci < 16; ++ci) mx = fmaxf(mx, acc[qq][ci]);
#pragma unroll
    for (int off = 32; off > 0; off >>= 1) mx = fmaxf(mx, __shfl_xor(mx, off, 64));
    float sum = 0.f;
#pragma unroll
    for (int ci = 0; ci < 16; ++ci) {
      const float p = __expf(acc[qq][ci] - mx);   // all-masked row -> uniform, matches ref
      acc[qq][ci] = p;
      sum += p;
    }
#pragma unroll
    for (int off = 32; off > 0; off >>= 1) sum += __shfl_xor(sum, off, 64);
    const float inv = 1.0f / sum;
#pragma unroll
    for (int ci = 0; ci < 16; ++ci) acc[qq][ci] *= inv;
    // write attn row slice: 64 consecutive lanes -> 256B coalesced stores
    float* ar = outAttn + mbase + (size_t)(8 * qg + qq) * S_ + kl;
#pragma unroll
    for (int ci = 0; ci < 16; ++ci) ar[64 * ci] = acc[qq][ci];
  }

  // ---- Phase 2: context = attn @ V (V tile 0 already in flight in st) ----
  const int qB = t >> 4, d4B = t & 15;   // thread owns rows qB, qB+16; 4 d-cols
  float4 c0 = {0.f, 0.f, 0.f, 0.f};
  float4 c1 = {0.f, 0.f, 0.f, 0.f};
#pragma unroll
  for (int vt = 0; vt < 8; ++vt) {
    __syncthreads();                      // previous tile fully consumed
#pragma unroll
    for (int i = 0; i < 8; ++i) {
      const int fi = t + 256 * i;
      KVs[fi >> 4][fi & 15] = st[i];
    }
    if (vt < 7) {                         // prefetch next V tile
#pragma unroll
      for (int i = 0; i < 8; ++i) st[i] = Vb4[(vt + 1) * 2048 + t + 256 * i];
    }
#pragma unroll
    for (int qq = 0; qq < 8; ++qq) {      // dump attn chunk (k in this tile)
      As[8 * qg + qq][kl]      = acc[qq][2 * vt];
      As[8 * qg + qq][kl + 64] = acc[qq][2 * vt + 1];
    }
    __syncthreads();
#pragma unroll 16
    for (int k_local = 0; k_local < 128; ++k_local) {
      const float  a0 = As[qB][k_local];       // broadcast within 16-lane group
      const float  a1 = As[qB + 16][k_local];
      const float4 vv = KVs[k_local][d4B];
      c0.x += a0 * vv.x; c0.y += a0 * vv.y; c0.z += a0 * vv.z; c0.w += a0 * vv.w;
      c1.x += a1 * vv.x; c1.y += a1 * vv.y; c1.z += a1 * vv.z; c1.w += a1 * vv.w;
    }
  }
  // context write: lanes 0..15 -> consecutive float4 (256B coalesced)
  float* ctx = out + (size_t)bh * (S_ * D_);
  ((float4*)(ctx + (size_t)(q0 + qB) * D_))[d4B]      = c0;
  ((float4*)(ctx + (size_t)(q0 + qB + 16) * D_))[d4B] = c1;
}

extern "C" void kernel_launch(void* const* d_in, const int* in_sizes, int n_in,
                              void* d_out, int out_size, void* d_ws, size_t ws_size,
                              hipStream_t stream) {
  const float* Q = (const float*)d_in[0];
  const float* K = (const float*)d_in[1];
  const float* V = (const float*)d_in[2];
  const void* mask = d_in[3];
  int* flag = (int*)d_ws;

  detect_mask_kernel<<<1, 256, 0, stream>>>((const unsigned int*)mask, flag);

  dim3 grid(32 * 128);   // 1D; XCD-aware decode inside the kernel
  attn_fused_kernel<<<grid, 256, 0, stream>>>(Q, K, V, mask, (float*)d_out, flag);
}